// Round 10
// baseline (99.775 us; speedup 1.0000x reference)
//
#include <hip/hip_runtime.h>

// GRU encoder, MI355X — R10 = R9 with the tile-B zero-init OOB bug fixed
// (hA32[4096+..] -> hA32[2048+..]; was zeroing past hA into xl and leaving
// tile B's h(0) garbage -> NaN).
// Structure: two 16-row tiles per wave, PHASE-PIPELINED across the barrier:
//   alpha(t): MFMA_A(t) || PW_B(t-1)  -> bar
//   beta(t):  MFMA_B(t) || PW_A(t)    -> bar
// MFMA and pointwise in every phase are from different tiles -> independent streams.
// Geometry: 256 blocks x 512 thr, BB=32, 8-way col split, 2 waves/SIMD.
// Carried: exp2-form gates, C-init injection, swizzled dbuf LDS h, lgkm-only barrier.

typedef __bf16 bf16x8 __attribute__((ext_vector_type(8)));
typedef float  f32x4  __attribute__((ext_vector_type(4)));
typedef int    int4v  __attribute__((ext_vector_type(4)));
typedef unsigned int uint2v __attribute__((ext_vector_type(2)));

#define NV   1000
#define EMB  64
#define HD   128
#define G3   384
#define SEQ  64
#define BB   32   // batch rows per block = 2 tiles x 16

#define SC_RZ (-1.4426950408889634f)   // -log2(e): sigmoid(s)=rcp(1+exp2(-log2e*s))
#define SC_N  ( 2.8853900817779268f)   // +2log2(e): tanh(v)=1-2*rcp(1+exp2(2log2e*v))

#define EXP2F(x) __builtin_amdgcn_exp2f(x)
#define RCPF(x)  __builtin_amdgcn_rcpf(x)

__device__ __forceinline__ float bflo(unsigned int word) {
    return __builtin_bit_cast(float, word << 16);
}
__device__ __forceinline__ float bfhi(unsigned int word) {
    return __builtin_bit_cast(float, word & 0xffff0000u);
}

// Gpk[v][w8][c16][slot]: slots {0,1,2} = scaled {xr',xz',xn'} for hid=w8*16+c16.
__global__ void g_table_kernel(const float* __restrict__ embed,
                               const float* __restrict__ W_ih,
                               const float* __restrict__ b_ih,
                               const float* __restrict__ b_hh,
                               unsigned short* __restrict__ Gpk)
{
    __shared__ float emb[EMB];
    const int v = blockIdx.x;
    const int g = threadIdx.x;              // 0..383 = gate*128 + hid
    if (g < EMB) emb[g] = embed[v * EMB + g];
    __syncthreads();
    const float* wr = W_ih + g * EMB;
    float s = b_ih[g] + (g < 2 * HD ? b_hh[g] : 0.f);   // fold b_hh for r,z only
    #pragma unroll
    for (int e = 0; e < EMB; e += 4) {
        const float4 w4 = *(const float4*)(wr + e);
        s += w4.x * emb[e] + w4.y * emb[e + 1] + w4.z * emb[e + 2] + w4.w * emb[e + 3];
    }
    const int hid = g & 127, gate = g >> 7;
    s *= (gate < 2) ? SC_RZ : SC_N;                      // pre-scale for exp2-form gates
    const int w8 = hid >> 4, c16i = hid & 15;
    Gpk[((v * 8 + w8) * 16 + c16i) * 4 + gate] =
        __builtin_bit_cast(unsigned short, (__bf16)s);
}

// pointwise for one tile's 4 elems: consumes ACC/XN, updates HR, writes LDS at WBASE
#define GRU_PW(ACC, XN, HR, WBASE)                                                 \
    _Pragma("unroll") for (int j = 0; j < 4; ++j) {                                \
      const float r  = RCPF(1.f + EXP2F(ACC[0][j]));                               \
      const float zg = RCPF(1.f + EXP2F(ACC[1][j]));                               \
      const float v  = __builtin_fmaf(r, ACC[2][j], XN[j]);                        \
      const float n  = __builtin_fmaf(-2.f, RCPF(1.f + EXP2F(v)), 1.f);            \
      const float hn = __builtin_fmaf(zg, HR[j] - n, n);                           \
      HR[j] = hn;                                                                  \
      *(unsigned short*)((WBASE) + woff[j]) =                                      \
          __builtin_bit_cast(unsigned short, (__bf16)hn);                          \
    }

// alpha(T): MFMA tile A @ parity P; PW tile B (T-1) write parity P; prefetch pfA(T+1)
#define PHASE_A(P, T)                                                              \
  {                                                                                \
    int4v tkA = {0, 0, 0, 0};                                                      \
    if ((T) < SEQ - 1) tkA = *(const int4v*)&xl[((T) + 1) * BB + quad * 4];        \
    _Pragma("unroll") for (int j = 0; j < 4; ++j) {                                \
      accA[0][j] = bflo(pfA[j][0]);                                                \
      accA[1][j] = bfhi(pfA[j][0]);                                                \
      accA[2][j] = bnw;                                                            \
      xnA[j]     = bflo(pfA[j][1]);                                                \
    }                                                                              \
    _Pragma("unroll") for (int ks = 0; ks < 4; ++ks) {                             \
      const bf16x8 af = *(const bf16x8*)(hbase + (P) * 4096 + aoff[ks]);           \
      _Pragma("unroll") for (int gate = 0; gate < 3; ++gate)                       \
        accA[gate] = __builtin_amdgcn_mfma_f32_16x16x32_bf16(                      \
            af, wf[gate][ks], accA[gate], 0, 0, 0);                                \
    }                                                                              \
    if ((T) < SEQ - 1) {                                                           \
      _Pragma("unroll") for (int j = 0; j < 4; ++j)                                \
        pfA[j] = *(const uint2v*)(gbase + (unsigned)(tkA[j] * 1024 + goff));       \
    }                                                                              \
    if ((T) > 0) {                                                                 \
      GRU_PW(accB, xnB, hregB, hbase + 8192 + (P) * 4096)                          \
    }                                                                              \
    asm volatile("s_waitcnt lgkmcnt(0)" ::: "memory");                             \
    __builtin_amdgcn_s_barrier();                                                  \
    __builtin_amdgcn_sched_barrier(0);                                             \
  }

// beta(T): MFMA tile B @ parity P; PW tile A (T) write parity 1-P; prefetch pfB(T+1)
#define PHASE_B(P, T)                                                              \
  {                                                                                \
    int4v tkB = {0, 0, 0, 0};                                                      \
    if ((T) < SEQ - 1) tkB = *(const int4v*)&xl[((T) + 1) * BB + 16 + quad * 4];   \
    _Pragma("unroll") for (int j = 0; j < 4; ++j) {                                \
      accB[0][j] = bflo(pfB[j][0]);                                                \
      accB[1][j] = bfhi(pfB[j][0]);                                                \
      accB[2][j] = bnw;                                                            \
      xnB[j]     = bflo(pfB[j][1]);                                                \
    }                                                                              \
    _Pragma("unroll") for (int ks = 0; ks < 4; ++ks) {                             \
      const bf16x8 af = *(const bf16x8*)(hbase + 8192 + (P) * 4096 + aoff[ks]);    \
      _Pragma("unroll") for (int gate = 0; gate < 3; ++gate)                       \
        accB[gate] = __builtin_amdgcn_mfma_f32_16x16x32_bf16(                      \
            af, wf[gate][ks], accB[gate], 0, 0, 0);                                \
    }                                                                              \
    if ((T) < SEQ - 1) {                                                           \
      _Pragma("unroll") for (int j = 0; j < 4; ++j)                                \
        pfB[j] = *(const uint2v*)(gbase + (unsigned)(tkB[j] * 1024 + goff));       \
    }                                                                              \
    GRU_PW(accA, xnA, hregA, hbase + (1 - (P)) * 4096)                             \
    asm volatile("s_waitcnt lgkmcnt(0)" ::: "memory");                             \
    __builtin_amdgcn_s_barrier();                                                  \
    __builtin_amdgcn_sched_barrier(0);                                             \
  }

__global__ __launch_bounds__(512, 2) void gru_kernel(
    const int*   __restrict__ x,    const unsigned short* __restrict__ Gpk,
    const float* __restrict__ Whh,  const float* __restrict__ bhh,
    const float* __restrict__ Wout, const float* __restrict__ bout,
    float* __restrict__ out)
{
    // hA layout: [tile(2)][parity(2)][4KB], frag-permuted + XOR swizzle per 4KB
    __shared__ unsigned short hA[2 * 2 * 16 * HD];   // 16 KB = 4096 dwords
    __shared__ int xl[SEQ * BB];                     // 8 KB, [t][row 0..31]

    const int tid  = threadIdx.x;
    const int lane = tid & 63;
    const int w    = tid >> 6;      // wave id 0..7 = 16-col team (per gate)
    const int c16  = lane & 15;
    const int quad = lane >> 4;
    const int br0  = blockIdx.x * BB;

    // ---- stage tokens transposed: xl[t*BB + r] = x[(br0+r)*SEQ + t]
    #pragma unroll
    for (int i = 0; i < 4; ++i) {
        const int idx = i * 512 + tid;     // 0..2047
        const int r = idx >> 6;            // 0..31
        const int t = idx & 63;
        xl[t * BB + r] = x[(br0 + r) * SEQ + t];
    }
    // ---- zero both tiles' parity-0 h buffers (h0 = 0)
    //      tile A par0 = dwords 0..1023; tile B par0 = dwords 2048..3071
    {
        unsigned int* hA32 = (unsigned int*)hA;
        #pragma unroll
        for (int i = 0; i < 2; ++i) {
            hA32[i * 512 + tid] = 0u;          // tile A parity0
            hA32[2048 + i * 512 + tid] = 0u;   // tile B parity0  (R9 bug: was 4096+)
        }
    }

    // ---- W_hh B-fragments: cols gate*128 + w*16 + c16 (gate-scaled)
    bf16x8 wf[3][4];
    #pragma unroll
    for (int gate = 0; gate < 3; ++gate)
    #pragma unroll
    for (int ks = 0; ks < 4; ++ks) {
        const float sc = (gate < 2) ? SC_RZ : SC_N;
        const int col = gate * HD + w * 16 + c16;
        const float* p = Whh + col * HD + ks * 32 + quad * 4;
        const float4 a = *(const float4*)p;
        const float4 b = *(const float4*)(p + 16);
        bf16x8 f;
        f[0] = (__bf16)(sc * a.x); f[1] = (__bf16)(sc * a.y);
        f[2] = (__bf16)(sc * a.z); f[3] = (__bf16)(sc * a.w);
        f[4] = (__bf16)(sc * b.x); f[5] = (__bf16)(sc * b.y);
        f[6] = (__bf16)(sc * b.z); f[7] = (__bf16)(sc * b.w);
        wf[gate][ks] = f;
    }

    const float bnw = SC_N * bhh[2 * HD + w * 16 + c16];   // scaled n-bias, this col

    // ---- hoisted per-lane-constant LDS offsets (within a 4KB tile-parity buffer)
    int aoff[4];
    #pragma unroll
    for (int ks = 0; ks < 4; ++ks)
        aoff[ks] = c16 * 256 + ((ks * 64 + quad * 16) ^ ((c16 & 7) << 4));
    int woff[4];
    {
        const int hid  = w * 16 + c16;
        const int sidx = ((hid >> 5) << 5) | (((hid & 15) >> 2) << 3)
                       | (((hid >> 4) & 1) << 2) | (hid & 3);
        #pragma unroll
        for (int j = 0; j < 4; ++j) {
            const int row = quad * 4 + j;
            woff[j] = row * 256 + ((sidx * 2) ^ ((row & 7) << 4));
        }
    }

    char* hbase = (char*)hA;
    const char* gbase = (const char*)Gpk;
    const int goff = w * 128 + c16 * 8;    // byte offset within a 1024B table row

    float hregA[4] = {0.f, 0.f, 0.f, 0.f};
    float hregB[4] = {0.f, 0.f, 0.f, 0.f};
    f32x4 accA[3], accB[3];
    float xnA[4], xnB[4];
    const f32x4 z4 = {0.f, 0.f, 0.f, 0.f};
    #pragma unroll
    for (int g2 = 0; g2 < 3; ++g2) { accA[g2] = z4; accB[g2] = z4; }
    #pragma unroll
    for (int j = 0; j < 4; ++j) { xnA[j] = 0.f; xnB[j] = 0.f; }

    __syncthreads();   // xl + hA zeros visible (one-time full drain is fine)

    // ---- preload xg(t=0) for both tiles
    uint2v pfA[4], pfB[4];
    {
        const int4v tA = *(const int4v*)&xl[0 * BB + quad * 4];
        const int4v tB = *(const int4v*)&xl[0 * BB + 16 + quad * 4];
        #pragma unroll
        for (int j = 0; j < 4; ++j)
            pfA[j] = *(const uint2v*)(gbase + (unsigned)(tA[j] * 1024 + goff));
        #pragma unroll
        for (int j = 0; j < 4; ++j)
            pfB[j] = *(const uint2v*)(gbase + (unsigned)(tB[j] * 1024 + goff));
    }

    for (int tt = 0; tt < SEQ; tt += 2) {
        PHASE_A(0, tt)       // MFMA_A(t) par0 ; PW_B(t-1) -> tileB par0
        PHASE_B(0, tt)       // MFMA_B(t) par0 ; PW_A(t)   -> tileA par1
        PHASE_A(1, tt + 1)   // MFMA_A(t+1) par1 ; PW_B(t) -> tileB par1
        PHASE_B(1, tt + 1)   // MFMA_B(t+1) par1 ; PW_A(t+1) -> tileA par0
    }
    // tail: PW_B(63) -> tile B parity 0 (accB/xnB from PHASE_B(1,63))
    GRU_PW(accB, xnB, hregB, hbase + 8192)
    __syncthreads();
    // h_final: tile A parity 0 (offset 0), tile B parity 0 (offset 8192)

    // ---- epilogue: out = h_final @ W_out^T + b_out (wave's 16 cols, both tiles)
    bf16x8 wo[4];
    #pragma unroll
    for (int ks = 0; ks < 4; ++ks) {
        const int col = w * 16 + c16;
        const float* p = Wout + col * HD + ks * 32 + quad * 4;
        const float4 a = *(const float4*)p;
        const float4 b = *(const float4*)(p + 16);
        bf16x8 f;
        f[0] = (__bf16)a.x; f[1] = (__bf16)a.y; f[2] = (__bf16)a.z; f[3] = (__bf16)a.w;
        f[4] = (__bf16)b.x; f[5] = (__bf16)b.y; f[6] = (__bf16)b.z; f[7] = (__bf16)b.w;
        wo[ks] = f;
    }
    const float bow = bout[w * 16 + c16];

    f32x4 oaccA = z4, oaccB = z4;
    #pragma unroll
    for (int ks = 0; ks < 4; ++ks) {
        const bf16x8 afA = *(const bf16x8*)(hbase + aoff[ks]);
        const bf16x8 afB = *(const bf16x8*)(hbase + 8192 + aoff[ks]);
        oaccA = __builtin_amdgcn_mfma_f32_16x16x32_bf16(afA, wo[ks], oaccA, 0, 0, 0);
        oaccB = __builtin_amdgcn_mfma_f32_16x16x32_bf16(afB, wo[ks], oaccB, 0, 0, 0);
    }
    #pragma unroll
    for (int j = 0; j < 4; ++j) {
        const int row = br0 + quad * 4 + j;
        out[row * HD + w * 16 + c16] = oaccA[j] + bow;
        out[(row + 16) * HD + w * 16 + c16] = oaccB[j] + bow;
    }
}

extern "C" void kernel_launch(void* const* d_in, const int* in_sizes, int n_in,
                              void* d_out, int out_size, void* d_ws, size_t ws_size,
                              hipStream_t stream) {
    const int*   x     = (const int*)  d_in[0];
    const float* embed = (const float*)d_in[1];
    const float* W_ih  = (const float*)d_in[2];
    const float* W_hh  = (const float*)d_in[3];
    const float* b_ih  = (const float*)d_in[4];
    const float* b_hh  = (const float*)d_in[5];
    const float* W_out = (const float*)d_in[6];
    const float* b_out = (const float*)d_in[7];
    float* outp = (float*)d_out;
    unsigned short* Gpk = (unsigned short*)d_ws;   // 1000*8*16*4*2B = 1.024 MB

    const int Bsz = in_sizes[0] / SEQ;             // 8192

    g_table_kernel<<<NV, G3, 0, stream>>>(embed, W_ih, b_ih, b_hh, Gpk);
    gru_kernel<<<Bsz / BB, 512, 0, stream>>>(x, Gpk, W_hh, b_hh, W_out, b_out, outp);
}

// Round 11
// 98.943 us; speedup vs baseline: 1.0084x; 1.0084x over previous
//
#include <hip/hip_runtime.h>

// GRU encoder, MI355X — R11 = R8 (best, 94.4us) + cross-block phase stagger.
// Odd blocks s_sleep ~1856cy once before the loop -> the 2 co-resident blocks per CU
// run in anti-phase, so each SIMD always hosts waves in complementary phases
// (PW burst vs MFMA/latency window). Single-variable change vs R8.
// Carried: 8-way col split, BB=16, 512thr, 2 blk/CU; exp2-form gates, C-init
// injection, swizzled dbuf LDS h, one raw s_barrier/step with lgkm-only drain.

typedef __bf16 bf16x8 __attribute__((ext_vector_type(8)));
typedef float  f32x4  __attribute__((ext_vector_type(4)));
typedef int    int4v  __attribute__((ext_vector_type(4)));
typedef unsigned int uint2v __attribute__((ext_vector_type(2)));

#define NV   1000
#define EMB  64
#define HD   128
#define G3   384
#define SEQ  64
#define BB   16   // batch rows per block

#define SC_RZ (-1.4426950408889634f)   // -log2(e): sigmoid(s)=rcp(1+exp2(-log2e*s))
#define SC_N  ( 2.8853900817779268f)   // +2log2(e): tanh(v)=1-2*rcp(1+exp2(2log2e*v))

__device__ __forceinline__ float bflo(unsigned int word) {
    return __builtin_bit_cast(float, word << 16);
}
__device__ __forceinline__ float bfhi(unsigned int word) {
    return __builtin_bit_cast(float, word & 0xffff0000u);
}

// Gpk[v][w8][c16][slot]: slots {0,1,2} = scaled {xr',xz',xn'} for hid=w8*16+c16.
__global__ void g_table_kernel(const float* __restrict__ embed,
                               const float* __restrict__ W_ih,
                               const float* __restrict__ b_ih,
                               const float* __restrict__ b_hh,
                               unsigned short* __restrict__ Gpk)
{
    __shared__ float emb[EMB];
    const int v = blockIdx.x;
    const int g = threadIdx.x;              // 0..383 = gate*128 + hid
    if (g < EMB) emb[g] = embed[v * EMB + g];
    __syncthreads();
    const float* wr = W_ih + g * EMB;
    float s = b_ih[g] + (g < 2 * HD ? b_hh[g] : 0.f);   // fold b_hh for r,z only
    #pragma unroll
    for (int e = 0; e < EMB; e += 4) {
        const float4 w4 = *(const float4*)(wr + e);
        s += w4.x * emb[e] + w4.y * emb[e + 1] + w4.z * emb[e + 2] + w4.w * emb[e + 3];
    }
    const int hid = g & 127, gate = g >> 7;
    s *= (gate < 2) ? SC_RZ : SC_N;                      // pre-scale for exp2-form gates
    const int w8 = hid >> 4, c16i = hid & 15;
    Gpk[((v * 8 + w8) * 16 + c16i) * 4 + gate] =
        __builtin_bit_cast(unsigned short, (__bf16)s);
}

// one GRU timestep. P = read-parity (compile-time), T = timestep.
#define GRU_STEP(P, T)                                                             \
  {                                                                                \
    int4v tk = {0, 0, 0, 0};                                                       \
    if ((T) < SEQ - 1) tk = *(const int4v*)&xl[((T) + 1) * BB + quad * 4];         \
    f32x4 acc[3];                                                                  \
    float xn_[4];                                                                  \
    _Pragma("unroll") for (int j = 0; j < 4; ++j) {                                \
      acc[0][j] = bflo(pf[j][0]);    /* xr' */                                     \
      acc[1][j] = bfhi(pf[j][0]);    /* xz' */                                     \
      acc[2][j] = bnw;               /* bn' */                                     \
      xn_[j]    = bflo(pf[j][1]);    /* xn' */                                     \
    }                                                                              \
    _Pragma("unroll") for (int ks = 0; ks < 4; ++ks) {                             \
      const bf16x8 af = *(const bf16x8*)(hbase + (P) * 4096 + aoff[ks]);           \
      _Pragma("unroll") for (int gate = 0; gate < 3; ++gate)                       \
        acc[gate] = __builtin_amdgcn_mfma_f32_16x16x32_bf16(                       \
            af, wf[gate][ks], acc[gate], 0, 0, 0);                                 \
    }                                                                              \
    if ((T) < SEQ - 1) {                                                           \
      _Pragma("unroll") for (int j = 0; j < 4; ++j)                                \
        pf[j] = *(const uint2v*)(gbase + (unsigned)(tk[j] * 1024 + goff));         \
    }                                                                              \
    _Pragma("unroll") for (int j = 0; j < 4; ++j) {                                \
      const float r  = __builtin_amdgcn_rcpf(                                      \
          1.f + __builtin_amdgcn_exp2f(acc[0][j]));                                \
      const float zg = __builtin_amdgcn_rcpf(                                      \
          1.f + __builtin_amdgcn_exp2f(acc[1][j]));                                \
      const float v  = __builtin_fmaf(r, acc[2][j], xn_[j]);                       \
      const float n  = __builtin_fmaf(-2.f,                                        \
          __builtin_amdgcn_rcpf(1.f + __builtin_amdgcn_exp2f(v)), 1.f);            \
      const float hn = __builtin_fmaf(zg, hreg[j] - n, n);                         \
      hreg[j] = hn;                                                                \
      *(unsigned short*)(hbase + (1 - (P)) * 4096 + woff[j]) =                     \
          __builtin_bit_cast(unsigned short, (__bf16)hn);                          \
    }                                                                              \
    asm volatile("s_waitcnt lgkmcnt(0)" ::: "memory");                             \
    __builtin_amdgcn_s_barrier();                                                  \
    __builtin_amdgcn_sched_barrier(0);                                             \
  }

__global__ __launch_bounds__(512, 4) void gru_kernel(
    const int*   __restrict__ x,    const unsigned short* __restrict__ Gpk,
    const float* __restrict__ Whh,  const float* __restrict__ bhh,
    const float* __restrict__ Wout, const float* __restrict__ bout,
    float* __restrict__ out)
{
    __shared__ unsigned short hA[2 * BB * HD];   // 2 x 4KB, frag-permuted + XOR swizzle
    __shared__ int xl[SEQ * BB];                 // 4KB, [t][row]

    const int tid  = threadIdx.x;
    const int lane = tid & 63;
    const int w    = tid >> 6;      // wave id 0..7 = 16-col team (per gate)
    const int c16  = lane & 15;
    const int quad = lane >> 4;
    const int br0  = blockIdx.x * BB;

    // ---- stage tokens transposed: xl[t*BB + r] = x[(br0+r)*SEQ + t]
    #pragma unroll
    for (int i = 0; i < 2; ++i) {
        const int idx = i * 512 + tid;     // 0..1023
        const int r = idx >> 6;            // 0..15
        const int t = idx & 63;
        xl[t * BB + r] = x[(br0 + r) * SEQ + t];
    }
    // ---- zero parity-0 h buffer (h0 = 0): 1024 dwords
    {
        unsigned int* hA32 = (unsigned int*)hA;
        #pragma unroll
        for (int i = 0; i < 2; ++i)
            hA32[i * 512 + tid] = 0u;
    }

    // ---- W_hh B-fragments: cols gate*128 + w*16 + c16 (gate-scaled)
    bf16x8 wf[3][4];
    #pragma unroll
    for (int gate = 0; gate < 3; ++gate)
    #pragma unroll
    for (int ks = 0; ks < 4; ++ks) {
        const float sc = (gate < 2) ? SC_RZ : SC_N;
        const int col = gate * HD + w * 16 + c16;
        const float* p = Whh + col * HD + ks * 32 + quad * 4;
        const float4 a = *(const float4*)p;
        const float4 b = *(const float4*)(p + 16);
        bf16x8 f;
        f[0] = (__bf16)(sc * a.x); f[1] = (__bf16)(sc * a.y);
        f[2] = (__bf16)(sc * a.z); f[3] = (__bf16)(sc * a.w);
        f[4] = (__bf16)(sc * b.x); f[5] = (__bf16)(sc * b.y);
        f[6] = (__bf16)(sc * b.z); f[7] = (__bf16)(sc * b.w);
        wf[gate][ks] = f;
    }

    const float bnw = SC_N * bhh[2 * HD + w * 16 + c16];   // scaled n-bias, this col

    // ---- hoisted per-lane-constant LDS offsets
    int aoff[4];
    #pragma unroll
    for (int ks = 0; ks < 4; ++ks)
        aoff[ks] = c16 * 256 + ((ks * 64 + quad * 16) ^ ((c16 & 7) << 4));
    int woff[4];
    {
        const int hid  = w * 16 + c16;
        const int sidx = ((hid >> 5) << 5) | (((hid & 15) >> 2) << 3)
                       | (((hid >> 4) & 1) << 2) | (hid & 3);
        #pragma unroll
        for (int j = 0; j < 4; ++j) {
            const int row = quad * 4 + j;
            woff[j] = row * 256 + ((sidx * 2) ^ ((row & 7) << 4));
        }
    }

    char* hbase = (char*)hA;
    const char* gbase = (const char*)Gpk;
    const int goff = w * 128 + c16 * 8;    // byte offset within a 1024B table row

    float hreg[4] = {0.f, 0.f, 0.f, 0.f};
    const f32x4 z4 = {0.f, 0.f, 0.f, 0.f};

    __syncthreads();   // xl + hA zeros visible (one-time full drain is fine)

    // ---- preload xg for t=0
    uint2v pf[4];
    {
        const int4v tk0 = *(const int4v*)&xl[0 * BB + quad * 4];
        #pragma unroll
        for (int j = 0; j < 4; ++j)
            pf[j] = *(const uint2v*)(gbase + (unsigned)(tk0[j] * 1024 + goff));
    }

    // ---- cross-block phase stagger: odd blocks shift by ~half a step (~1856cy)
    // so the 2 co-resident blocks per CU run in anti-phase (complementary pipe use).
    if (blockIdx.x & 1) {
        __builtin_amdgcn_s_sleep(29);
    }

    for (int tt = 0; tt < SEQ; tt += 2) {
        GRU_STEP(0, tt);       // reads parity 0, writes parity 1
        GRU_STEP(1, tt + 1);   // reads parity 1, writes parity 0
    }
    // after t=63 (odd): h_final in parity-0 buffer.

    // ---- epilogue: out = h_final @ W_out^T + b_out (wave's 16 cols)
    bf16x8 wo[4];
    #pragma unroll
    for (int ks = 0; ks < 4; ++ks) {
        const int col = w * 16 + c16;
        const float* p = Wout + col * HD + ks * 32 + quad * 4;
        const float4 a = *(const float4*)p;
        const float4 b = *(const float4*)(p + 16);
        bf16x8 f;
        f[0] = (__bf16)a.x; f[1] = (__bf16)a.y; f[2] = (__bf16)a.z; f[3] = (__bf16)a.w;
        f[4] = (__bf16)b.x; f[5] = (__bf16)b.y; f[6] = (__bf16)b.z; f[7] = (__bf16)b.w;
        wo[ks] = f;
    }
    const float bow = bout[w * 16 + c16];

    f32x4 oacc = z4;
    #pragma unroll
    for (int ks = 0; ks < 4; ++ks) {
        const bf16x8 af = *(const bf16x8*)(hbase + aoff[ks]);   // parity 0
        oacc = __builtin_amdgcn_mfma_f32_16x16x32_bf16(af, wo[ks], oacc, 0, 0, 0);
    }
    #pragma unroll
    for (int j = 0; j < 4; ++j) {
        const int row = br0 + quad * 4 + j;
        out[row * HD + w * 16 + c16] = oacc[j] + bow;
    }
}

extern "C" void kernel_launch(void* const* d_in, const int* in_sizes, int n_in,
                              void* d_out, int out_size, void* d_ws, size_t ws_size,
                              hipStream_t stream) {
    const int*   x     = (const int*)  d_in[0];
    const float* embed = (const float*)d_in[1];
    const float* W_ih  = (const float*)d_in[2];
    const float* W_hh  = (const float*)d_in[3];
    const float* b_ih  = (const float*)d_in[4];
    const float* b_hh  = (const float*)d_in[5];
    const float* W_out = (const float*)d_in[6];
    const float* b_out = (const float*)d_in[7];
    float* outp = (float*)d_out;
    unsigned short* Gpk = (unsigned short*)d_ws;   // 1000*8*16*4*2B = 1.024 MB

    const int Bsz = in_sizes[0] / SEQ;             // 8192

    g_table_kernel<<<NV, G3, 0, stream>>>(embed, W_ih, b_ih, b_hh, Gpk);
    gru_kernel<<<Bsz / BB, 512, 0, stream>>>(x, Gpk, W_hh, b_hh, W_out, b_out, outp);
}